// Round 3
// baseline (1819.163 us; speedup 1.0000x reference)
//
#include <hip/hip_runtime.h>
#include <math.h>

// ---------------------------------------------------------------------------
// ViT encoder block. Split-bf16 MFMA GEMMs + fp32 VALU flash attention.
// B=32, N=577, D=768, H=12, Dh=64, hid=3072, M=18464, Mp=18560 (pad to 145*128)
//
// fp32 GEMM via 3x bf16 MFMA: x = hi + lo (bf16 RNE split);
//   A@B ~= Ahi@Bhi + Ahi@Blo + Alo@Bhi   (error <= 2^-16 per product)
//
// ws layout (bytes, 256-aligned regions), ~255.5 MB total:
//   W*: transposed split weights  (28.3 MB)
//   A_h/A_l: [Mp][768] bf16 activation hi/lo (57 MB)  -- ln1/attnO/ln2 reuse
//   R1: qkv fp32 [M][2304] (170.2 MB), later reused as fc1out hi/lo chunks
// ---------------------------------------------------------------------------

typedef unsigned short u16;
typedef __attribute__((ext_vector_type(8))) short bf16x8;
typedef __attribute__((ext_vector_type(4))) float f32x4;

__device__ __forceinline__ u16 f2bf(float x) {           // RNE f32 -> bf16
    unsigned u = __float_as_uint(x);
    return (u16)((u + 0x7FFF + ((u >> 16) & 1)) >> 16);
}
__device__ __forceinline__ float bf2f(u16 h) {
    return __uint_as_float(((unsigned)h) << 16);
}

__device__ __forceinline__ void load_lds16(const u16* g, void* l) {
    __builtin_amdgcn_global_load_lds(
        (const __attribute__((address_space(1))) void*)g,
        (__attribute__((address_space(3))) void*)l, 16, 0, 0);
}

// --------------------- weight transpose + split (once) ---------------------
// W[K][N] fp32  ->  Th/Tl[N][K] bf16
__global__ __launch_bounds__(256)
void wprep_kernel(const float* __restrict__ W, u16* __restrict__ Th,
                  u16* __restrict__ Tl, int K, int N)
{
    __shared__ float t[32][33];
    const int n0 = blockIdx.x * 32, k0 = blockIdx.y * 32;
    const int tr = threadIdx.x >> 3, tc4 = (threadIdx.x & 7) * 4;
    const float4 v = *(const float4*)&W[(size_t)(k0 + tr) * N + n0 + tc4];
    t[tr][tc4 + 0] = v.x; t[tr][tc4 + 1] = v.y;
    t[tr][tc4 + 2] = v.z; t[tr][tc4 + 3] = v.w;
    __syncthreads();
    ushort4 h, l;
    float x0 = t[tc4 + 0][tr], x1 = t[tc4 + 1][tr];
    float x2 = t[tc4 + 2][tr], x3 = t[tc4 + 3][tr];
    h.x = f2bf(x0); l.x = f2bf(x0 - bf2f(h.x));
    h.y = f2bf(x1); l.y = f2bf(x1 - bf2f(h.y));
    h.z = f2bf(x2); l.z = f2bf(x2 - bf2f(h.z));
    h.w = f2bf(x3); l.w = f2bf(x3 - bf2f(h.w));
    const size_t o = (size_t)(n0 + tr) * K + k0 + tc4;
    *(ushort4*)&Th[o] = h;
    *(ushort4*)&Tl[o] = l;
}

// ------------------------- LayerNorm -> bf16 hi/lo --------------------------
__global__ __launch_bounds__(256)
void ln_kernel(const float* __restrict__ x, const float* __restrict__ g,
               const float* __restrict__ beta, u16* __restrict__ oh,
               u16* __restrict__ ol)
{
    const int row = blockIdx.x;
    const int tid = threadIdx.x;
    const float* xr = x + (size_t)row * 768;
    const float v0 = xr[tid], v1 = xr[tid + 256], v2 = xr[tid + 512];
    float s  = v0 + v1 + v2;
    float ss = v0 * v0 + v1 * v1 + v2 * v2;
    #pragma unroll
    for (int off = 1; off < 64; off <<= 1) {
        s  += __shfl_xor(s, off);
        ss += __shfl_xor(ss, off);
    }
    __shared__ float redS[4], redQ[4];
    const int wid = tid >> 6;
    if ((tid & 63) == 0) { redS[wid] = s; redQ[wid] = ss; }
    __syncthreads();
    s  = redS[0] + redS[1] + redS[2] + redS[3];
    ss = redQ[0] + redQ[1] + redQ[2] + redQ[3];
    const float mean = s * (1.0f / 768.0f);
    const float var  = ss * (1.0f / 768.0f) - mean * mean;
    const float rstd = rsqrtf(var + 1e-5f);
    u16* ohr = oh + (size_t)row * 768;
    u16* olr = ol + (size_t)row * 768;
    #pragma unroll
    for (int u = 0; u < 3; ++u) {
        const int c = tid + u * 256;
        const float vv = (u == 0) ? v0 : (u == 1) ? v1 : v2;
        const float y = (vv - mean) * rstd * g[c] + beta[c];
        const u16 h = f2bf(y);
        ohr[c] = h;
        olr[c] = f2bf(y - bf2f(h));
    }
}

// ------------------------- split-bf16 MFMA GEMM -----------------------------
// C[M][N] = (Ah+Al)[rows][K] @ (Bh+Bl)^T  + bias (+relu6) (+res)
// A: [*][K] bf16 hi/lo (rows padded to grid), B: [N][K] bf16 hi/lo (transposed)
// 128x128x32 tile, 256 threads = 4 waves (2x2), 4x4 frags of 16x16x32 / wave.
template<int RELU6, int RES, int OUT_PAIR>
__global__ __launch_bounds__(256)
void mfma_gemm(const u16* __restrict__ Ah, const u16* __restrict__ Al,
               const u16* __restrict__ Bh, const u16* __restrict__ Bl,
               const float* __restrict__ bias, const float* res,
               float* Cf, u16* __restrict__ Ch, u16* __restrict__ Cl,
               int M, int N, int K)
{
    __shared__ u16 lds[4 * 128 * 32];        // sAh | sAl | sBh | sBl (8KB each)
    u16* sAh = lds;
    u16* sAl = lds + 4096;
    u16* sBh = lds + 8192;
    u16* sBl = lds + 12288;

    const int tid  = threadIdx.x;
    const int wave = tid >> 6;
    const int lane = tid & 63;
    const int bm = blockIdx.y * 128;
    const int bn = blockIdx.x * 128;

    // ---- staging geometry: instr slice i covers tile rows i*64 + wave*16 + lane/4,
    // phys 16B-chunk c = lane&3; logical k-group kg = c ^ ((row>>1)&3) (XOR swizzle)
    const int r0 = wave * 16 + (lane >> 2);
    const int r1 = 64 + r0;
    const int c  = lane & 3;
    const int kg0 = c ^ ((r0 >> 1) & 3);
    const int kg1 = c ^ ((r1 >> 1) & 3);

    const u16* pA0h = Ah + (size_t)(bm + r0) * K + 8 * kg0;
    const u16* pA1h = Ah + (size_t)(bm + r1) * K + 8 * kg1;
    const u16* pA0l = Al + (size_t)(bm + r0) * K + 8 * kg0;
    const u16* pA1l = Al + (size_t)(bm + r1) * K + 8 * kg1;
    const u16* pB0h = Bh + (size_t)(bn + r0) * K + 8 * kg0;
    const u16* pB1h = Bh + (size_t)(bn + r1) * K + 8 * kg1;
    const u16* pB0l = Bl + (size_t)(bn + r0) * K + 8 * kg0;
    const u16* pB1l = Bl + (size_t)(bn + r1) * K + 8 * kg1;

    char* ldsb = (char*)lds;
    char* dA0h = ldsb +     0 + wave * 1024;
    char* dA1h = ldsb +  4096 + wave * 1024;
    char* dA0l = ldsb +  8192 + wave * 1024;
    char* dA1l = ldsb + 12288 + wave * 1024;
    char* dB0h = ldsb + 16384 + wave * 1024;
    char* dB1h = ldsb + 20480 + wave * 1024;
    char* dB0l = ldsb + 24576 + wave * 1024;
    char* dB1l = ldsb + 28672 + wave * 1024;

    const int am0 = (wave >> 1) * 64;   // A-tile row base of this wave
    const int bn0 = (wave & 1) * 64;    // B-tile row (=col) base of this wave
    const int l15 = lane & 15;
    const int lg  = lane >> 4;          // logical k-group of MFMA fragment reads

    f32x4 acc[4][4] = {};

    const int nk = K >> 5;
    for (int ks = 0; ks < nk; ++ks) {
        __syncthreads();
        load_lds16(pA0h, dA0h); load_lds16(pA1h, dA1h);
        load_lds16(pA0l, dA0l); load_lds16(pA1l, dA1l);
        load_lds16(pB0h, dB0h); load_lds16(pB1h, dB1h);
        load_lds16(pB0l, dB0l); load_lds16(pB1l, dB1l);
        pA0h += 32; pA1h += 32; pA0l += 32; pA1l += 32;
        pB0h += 32; pB1h += 32; pB0l += 32; pB1l += 32;
        __syncthreads();   // compiler drains vmcnt before s_barrier

        bf16x8 ah[4], al[4];
        #pragma unroll
        for (int fm = 0; fm < 4; ++fm) {
            const int ar = am0 + fm * 16 + l15;
            const int ph = (lg ^ ((ar >> 1) & 3)) * 8;
            ah[fm] = *(const bf16x8*)&sAh[ar * 32 + ph];
            al[fm] = *(const bf16x8*)&sAl[ar * 32 + ph];
        }
        #pragma unroll
        for (int fn = 0; fn < 4; ++fn) {
            const int br = bn0 + fn * 16 + l15;
            const int ph = (lg ^ ((br >> 1) & 3)) * 8;
            const bf16x8 bh = *(const bf16x8*)&sBh[br * 32 + ph];
            const bf16x8 bl = *(const bf16x8*)&sBl[br * 32 + ph];
            #pragma unroll
            for (int fm = 0; fm < 4; ++fm) {
                acc[fm][fn] = __builtin_amdgcn_mfma_f32_16x16x32_bf16(
                    ah[fm], bh, acc[fm][fn], 0, 0, 0);
                acc[fm][fn] = __builtin_amdgcn_mfma_f32_16x16x32_bf16(
                    ah[fm], bl, acc[fm][fn], 0, 0, 0);
                acc[fm][fn] = __builtin_amdgcn_mfma_f32_16x16x32_bf16(
                    al[fm], bh, acc[fm][fn], 0, 0, 0);
            }
        }
    }

    // ---- epilogue: D layout col = lane&15, row = (lane>>4)*4 + j (m89/m91)
    #pragma unroll
    for (int fn = 0; fn < 4; ++fn) {
        const int cc = bn + bn0 + fn * 16 + l15;
        const float bv = bias[cc];
        #pragma unroll
        for (int fm = 0; fm < 4; ++fm) {
            const int rbase = bm + am0 + fm * 16 + lg * 4;
            const f32x4 v = acc[fm][fn];
            #pragma unroll
            for (int j = 0; j < 4; ++j) {
                const int r = rbase + j;
                if (r < M) {
                    float o = v[j] + bv;
                    if (RELU6) o = fminf(fmaxf(o, 0.0f), 6.0f);
                    if (RES)   o += res[(size_t)r * N + cc];
                    if (OUT_PAIR) {
                        const u16 h = f2bf(o);
                        Ch[(size_t)r * N + cc] = h;
                        Cl[(size_t)r * N + cc] = f2bf(o - bf2f(h));
                    } else {
                        Cf[(size_t)r * N + cc] = o;
                    }
                }
            }
        }
    }
}

// --------------------------- Flash attention (fp32) -------------------------
// qkv fp32 [B*N][2304]; writes O as bf16 hi/lo [M][768] at col h*64.
__global__ __launch_bounds__(256)
void attn_kernel(const float* __restrict__ qkv, u16* __restrict__ Oh,
                 u16* __restrict__ Ol)
{
    constexpr int SEQ = 577, H = 12, D3 = 2304, DH = 64;
    const int qt = blockIdx.x;          // 0..9
    const int bh = blockIdx.y;          // 0..383
    const int b  = bh / H, h = bh % H;
    const int q0 = qt * 64;
    const int tid = threadIdx.x;

    __shared__ float Qt[64][68];  // Qt[d][r]
    __shared__ float Kt[64][68];  // Kt[d][c]
    __shared__ float Vs[64][68];  // Vs[j][d]
    __shared__ float Pt[64][68];  // Pt[j][r]

    const int lr  = tid >> 2;
    const int lc0 = (tid & 3) * 16;

    const float* base = qkv + (size_t)b * SEQ * D3 + h * DH;

    {
        const int n = q0 + lr;
        const float* src = base + (size_t)n * D3 + lc0;
        #pragma unroll
        for (int u = 0; u < 4; ++u) {
            const float4 q4 = (n < SEQ) ? *(const float4*)(src + u * 4)
                                        : make_float4(0.f, 0.f, 0.f, 0.f);
            Qt[lc0 + u * 4 + 0][lr] = q4.x;
            Qt[lc0 + u * 4 + 1][lr] = q4.y;
            Qt[lc0 + u * 4 + 2][lr] = q4.z;
            Qt[lc0 + u * 4 + 3][lr] = q4.w;
        }
    }

    const int tr4 = (tid >> 4) * 4;
    const int tc4 = (tid & 15) * 4;

    float acc[4][4] = {};
    float m_i[4] = {-1e30f, -1e30f, -1e30f, -1e30f};
    float l_i[4] = {0.f, 0.f, 0.f, 0.f};
    const float scale = 0.125f;

    for (int kv0 = 0; kv0 < SEQ; kv0 += 64) {
        const int kvn = (SEQ - kv0 < 64) ? (SEQ - kv0) : 64;
        __syncthreads();
        {
            const int n = kv0 + lr;
            const bool valn = n < SEQ;
            const float* ksrc = base + (size_t)n * D3 + 768  + lc0;
            const float* vsrc = base + (size_t)n * D3 + 1536 + lc0;
            #pragma unroll
            for (int u = 0; u < 4; ++u) {
                const float4 k4 = valn ? *(const float4*)(ksrc + u * 4)
                                       : make_float4(0.f, 0.f, 0.f, 0.f);
                Kt[lc0 + u * 4 + 0][lr] = k4.x;
                Kt[lc0 + u * 4 + 1][lr] = k4.y;
                Kt[lc0 + u * 4 + 2][lr] = k4.z;
                Kt[lc0 + u * 4 + 3][lr] = k4.w;
                const float4 v4 = valn ? *(const float4*)(vsrc + u * 4)
                                       : make_float4(0.f, 0.f, 0.f, 0.f);
                *(float4*)&Vs[lr][lc0 + u * 4] = v4;
            }
        }
        __syncthreads();

        float s[4][4] = {};
        #pragma unroll 8
        for (int kk = 0; kk < 64; ++kk) {
            const float4 a  = *(const float4*)&Qt[kk][tr4];
            const float4 bq = *(const float4*)&Kt[kk][tc4];
            const float ar[4] = {a.x, a.y, a.z, a.w};
            const float br[4] = {bq.x, bq.y, bq.z, bq.w};
            #pragma unroll
            for (int i = 0; i < 4; ++i)
                #pragma unroll
                for (int j = 0; j < 4; ++j)
                    s[i][j] = fmaf(ar[i], br[j], s[i][j]);
        }

        #pragma unroll
        for (int i = 0; i < 4; ++i) {
            float ps[4];
            #pragma unroll
            for (int j = 0; j < 4; ++j) {
                const float sv = s[i][j] * scale;
                ps[j] = (tc4 + j < kvn) ? sv : -1e30f;
            }
            float mx = fmaxf(fmaxf(ps[0], ps[1]), fmaxf(ps[2], ps[3]));
            #pragma unroll
            for (int off = 1; off < 16; off <<= 1)
                mx = fmaxf(mx, __shfl_xor(mx, off));
            const float mnew = fmaxf(m_i[i], mx);
            const float corr = expf(m_i[i] - mnew);
            float rs = 0.f;
            #pragma unroll
            for (int j = 0; j < 4; ++j) {
                ps[j] = expf(ps[j] - mnew);
                rs += ps[j];
            }
            #pragma unroll
            for (int off = 1; off < 16; off <<= 1)
                rs += __shfl_xor(rs, off);
            l_i[i] = l_i[i] * corr + rs;
            m_i[i] = mnew;
            #pragma unroll
            for (int j = 0; j < 4; ++j) acc[i][j] *= corr;
            #pragma unroll
            for (int j = 0; j < 4; ++j) Pt[tc4 + j][tr4 + i] = ps[j];
        }
        __syncthreads();

        #pragma unroll 8
        for (int jj = 0; jj < 64; ++jj) {
            const float4 pa = *(const float4*)&Pt[jj][tr4];
            const float4 vb = *(const float4*)&Vs[jj][tc4];
            const float pr[4] = {pa.x, pa.y, pa.z, pa.w};
            const float vr[4] = {vb.x, vb.y, vb.z, vb.w};
            #pragma unroll
            for (int i = 0; i < 4; ++i)
                #pragma unroll
                for (int j = 0; j < 4; ++j)
                    acc[i][j] = fmaf(pr[i], vr[j], acc[i][j]);
        }
    }

    #pragma unroll
    for (int i = 0; i < 4; ++i) {
        const int n = q0 + tr4 + i;
        if (n < SEQ) {
            const float inv = 1.0f / l_i[i];
            ushort4 hv, lv;
            const float o0 = acc[i][0] * inv, o1 = acc[i][1] * inv;
            const float o2 = acc[i][2] * inv, o3 = acc[i][3] * inv;
            hv.x = f2bf(o0); lv.x = f2bf(o0 - bf2f(hv.x));
            hv.y = f2bf(o1); lv.y = f2bf(o1 - bf2f(hv.y));
            hv.z = f2bf(o2); lv.z = f2bf(o2 - bf2f(hv.z));
            hv.w = f2bf(o3); lv.w = f2bf(o3 - bf2f(hv.w));
            const size_t idx = ((size_t)b * SEQ + n) * 768 + h * DH + tc4;
            *(ushort4*)&Oh[idx] = hv;
            *(ushort4*)&Ol[idx] = lv;
        }
    }
}

// ------------------------------- launch ------------------------------------
extern "C" void kernel_launch(void* const* d_in, const int* in_sizes, int n_in,
                              void* d_out, int out_size, void* d_ws, size_t ws_size,
                              hipStream_t stream)
{
    const float* x      = (const float*)d_in[0];
    const float* ln1_g  = (const float*)d_in[1];
    const float* ln1_b  = (const float*)d_in[2];
    const float* ln2_g  = (const float*)d_in[3];
    const float* ln2_b  = (const float*)d_in[4];
    const float* w_qkv  = (const float*)d_in[5];
    const float* b_qkv  = (const float*)d_in[6];
    const float* w_proj = (const float*)d_in[7];
    const float* b_proj = (const float*)d_in[8];
    const float* w_fc1  = (const float*)d_in[9];
    const float* b_fc1  = (const float*)d_in[10];
    const float* w_fc2  = (const float*)d_in[11];
    const float* b_fc2  = (const float*)d_in[12];
    float* out = (float*)d_out;

    const int M  = 18464;       // 32*577
    const int Mp = 18560;       // 145*128

    // ---- workspace carve-up (all sizes already 256B-aligned) ----
    char* p = (char*)d_ws;
    u16* Wqkv_h = (u16*)p;                 p += (size_t)2304 * 768 * 2;
    u16* Wqkv_l = (u16*)p;                 p += (size_t)2304 * 768 * 2;
    u16* Wproj_h = (u16*)p;                p += (size_t)768 * 768 * 2;
    u16* Wproj_l = (u16*)p;                p += (size_t)768 * 768 * 2;
    u16* Wfc1_h = (u16*)p;                 p += (size_t)3072 * 768 * 2;
    u16* Wfc1_l = (u16*)p;                 p += (size_t)3072 * 768 * 2;
    u16* Wfc2_h = (u16*)p;                 p += (size_t)768 * 3072 * 2;
    u16* Wfc2_l = (u16*)p;                 p += (size_t)768 * 3072 * 2;
    u16* A_h = (u16*)p;                    p += (size_t)Mp * 768 * 2;
    u16* A_l = (u16*)p;                    p += (size_t)Mp * 768 * 2;
    float* qkvf = (float*)p;               // 170.2 MB; reused below for fc1out
    u16* fc1h = (u16*)p;
    u16* fc1l = fc1h + (size_t)9344 * 3072;

    // ---- weight prep (transpose + bf16 split) ----
    wprep_kernel<<<dim3(2304 / 32, 768 / 32),  256, 0, stream>>>(w_qkv,  Wqkv_h,  Wqkv_l,  768, 2304);
    wprep_kernel<<<dim3(768 / 32,  768 / 32),  256, 0, stream>>>(w_proj, Wproj_h, Wproj_l, 768, 768);
    wprep_kernel<<<dim3(3072 / 32, 768 / 32),  256, 0, stream>>>(w_fc1,  Wfc1_h,  Wfc1_l,  768, 3072);
    wprep_kernel<<<dim3(768 / 32,  3072 / 32), 256, 0, stream>>>(w_fc2,  Wfc2_h,  Wfc2_l,  3072, 768);

    // ---- ln1 -> A ----
    ln_kernel<<<M, 256, 0, stream>>>(x, ln1_g, ln1_b, A_h, A_l);
    // ---- qkv = ln1 @ w_qkv + b : fp32 [M][2304] ----
    mfma_gemm<0, 0, 0><<<dim3(18, 145), 256, 0, stream>>>(
        A_h, A_l, Wqkv_h, Wqkv_l, b_qkv, nullptr, qkvf, nullptr, nullptr,
        M, 2304, 768);
    // ---- attention -> A (hi/lo) ----
    attn_kernel<<<dim3(10, 384), 256, 0, stream>>>(qkvf, A_h, A_l);
    // ---- x1 = attnO @ w_proj + b + x -> out ----
    mfma_gemm<0, 1, 0><<<dim3(6, 145), 256, 0, stream>>>(
        A_h, A_l, Wproj_h, Wproj_l, b_proj, x, out, nullptr, nullptr,
        M, 768, 768);
    // ---- ln2 -> A ----
    ln_kernel<<<M, 256, 0, stream>>>(out, ln2_g, ln2_b, A_h, A_l);
    // ---- MLP in 2 row chunks (hidden hi/lo reuses the qkv region) ----
    const int CH = 9344;   // 73*128
    for (int r0 = 0; r0 < M; r0 += CH) {
        const int mc = (M - r0 < CH) ? (M - r0) : CH;
        const int mtiles = (mc + 127) / 128;
        mfma_gemm<1, 0, 1><<<dim3(24, mtiles), 256, 0, stream>>>(
            A_h + (size_t)r0 * 768, A_l + (size_t)r0 * 768,
            Wfc1_h, Wfc1_l, b_fc1, nullptr, nullptr, fc1h, fc1l,
            mc, 3072, 768);
        mfma_gemm<0, 1, 0><<<dim3(6, mtiles), 256, 0, stream>>>(
            fc1h, fc1l, Wfc2_h, Wfc2_l, b_fc2,
            out + (size_t)r0 * 768, out + (size_t)r0 * 768, nullptr, nullptr,
            mc, 768, 3072);
    }
}

// Round 4
// 1424.746 us; speedup vs baseline: 1.2768x; 1.2768x over previous
//
#include <hip/hip_runtime.h>
#include <math.h>

// ---------------------------------------------------------------------------
// ViT encoder block. Split-bf16 MFMA for GEMMs AND attention.
// B=32, N=577, D=768, H=12, Dh=64, hid=3072, M=18464, Mp=18560.
// fp32 ~= hi + lo (bf16 RNE split); A@B ~= Ah@Bh + Ah@Bl + Al@Bh.
// ---------------------------------------------------------------------------

typedef unsigned short u16;
typedef __attribute__((ext_vector_type(8))) short bf16x8;
typedef __attribute__((ext_vector_type(4))) float f32x4;

__device__ __forceinline__ u16 f2bf(float x) {           // RNE f32 -> bf16
    unsigned u = __float_as_uint(x);
    return (u16)((u + 0x7FFF + ((u >> 16) & 1)) >> 16);
}
__device__ __forceinline__ float bf2f(u16 h) {
    return __uint_as_float(((unsigned)h) << 16);
}
__device__ __forceinline__ void load_lds16(const u16* g, void* l) {
    __builtin_amdgcn_global_load_lds(
        (const __attribute__((address_space(1))) void*)g,
        (__attribute__((address_space(3))) void*)l, 16, 0, 0);
}

// --------------------- weight transpose + split (once) ---------------------
__global__ __launch_bounds__(256)
void wprep_kernel(const float* __restrict__ W, u16* __restrict__ Th,
                  u16* __restrict__ Tl, int K, int N)
{
    __shared__ float t[32][33];
    const int n0 = blockIdx.x * 32, k0 = blockIdx.y * 32;
    const int tr = threadIdx.x >> 3, tc4 = (threadIdx.x & 7) * 4;
    const float4 v = *(const float4*)&W[(size_t)(k0 + tr) * N + n0 + tc4];
    t[tr][tc4 + 0] = v.x; t[tr][tc4 + 1] = v.y;
    t[tr][tc4 + 2] = v.z; t[tr][tc4 + 3] = v.w;
    __syncthreads();
    ushort4 h, l;
    float x0 = t[tc4 + 0][tr], x1 = t[tc4 + 1][tr];
    float x2 = t[tc4 + 2][tr], x3 = t[tc4 + 3][tr];
    h.x = f2bf(x0); l.x = f2bf(x0 - bf2f(h.x));
    h.y = f2bf(x1); l.y = f2bf(x1 - bf2f(h.y));
    h.z = f2bf(x2); l.z = f2bf(x2 - bf2f(h.z));
    h.w = f2bf(x3); l.w = f2bf(x3 - bf2f(h.w));
    const size_t o = (size_t)(n0 + tr) * K + k0 + tc4;
    *(ushort4*)&Th[o] = h;
    *(ushort4*)&Tl[o] = l;
}

// ------------------------- LayerNorm -> bf16 hi/lo --------------------------
__global__ __launch_bounds__(256)
void ln_kernel(const float* __restrict__ x, const float* __restrict__ g,
               const float* __restrict__ beta, u16* __restrict__ oh,
               u16* __restrict__ ol)
{
    const int row = blockIdx.x;
    const int tid = threadIdx.x;
    const float* xr = x + (size_t)row * 768;
    const float v0 = xr[tid], v1 = xr[tid + 256], v2 = xr[tid + 512];
    float s  = v0 + v1 + v2;
    float ss = v0 * v0 + v1 * v1 + v2 * v2;
    #pragma unroll
    for (int off = 1; off < 64; off <<= 1) {
        s  += __shfl_xor(s, off);
        ss += __shfl_xor(ss, off);
    }
    __shared__ float redS[4], redQ[4];
    const int wid = tid >> 6;
    if ((tid & 63) == 0) { redS[wid] = s; redQ[wid] = ss; }
    __syncthreads();
    s  = redS[0] + redS[1] + redS[2] + redS[3];
    ss = redQ[0] + redQ[1] + redQ[2] + redQ[3];
    const float mean = s * (1.0f / 768.0f);
    const float var  = ss * (1.0f / 768.0f) - mean * mean;
    const float rstd = rsqrtf(var + 1e-5f);
    u16* ohr = oh + (size_t)row * 768;
    u16* olr = ol + (size_t)row * 768;
    #pragma unroll
    for (int u = 0; u < 3; ++u) {
        const int c = tid + u * 256;
        const float vv = (u == 0) ? v0 : (u == 1) ? v1 : v2;
        const float y = (vv - mean) * rstd * g[c] + beta[c];
        const u16 h = f2bf(y);
        ohr[c] = h;
        olr[c] = f2bf(y - bf2f(h));
    }
}

// ------------------------- split-bf16 MFMA GEMM -----------------------------
// 128x128x32 tile, 4 waves, 4x4 frags of 16x16x32 per wave.
// OMODE: 0 = fp32 out (+res), 1 = bf16 hi/lo pair out, 2 = QKV scatter out.
template<int RELU6, int RES, int OMODE>
__global__ __launch_bounds__(256)
void mfma_gemm(const u16* __restrict__ Ah, const u16* __restrict__ Al,
               const u16* __restrict__ Bh, const u16* __restrict__ Bl,
               const float* __restrict__ bias, const float* res,
               float* Cf, u16* __restrict__ Ch, u16* __restrict__ Cl,
               u16* __restrict__ Qh_, u16* __restrict__ Ql_,
               u16* __restrict__ Kh_, u16* __restrict__ Kl_,
               u16* __restrict__ Vth_, u16* __restrict__ Vtl_,
               int M, int N, int K)
{
    __shared__ u16 lds[4 * 128 * 32];        // sAh | sAl | sBh | sBl (8KB each)
    u16* sAh = lds;
    u16* sAl = lds + 4096;
    u16* sBh = lds + 8192;
    u16* sBl = lds + 12288;

    const int tid  = threadIdx.x;
    const int wave = tid >> 6;
    const int lane = tid & 63;
    const int bm = blockIdx.y * 128;
    const int bn = blockIdx.x * 128;

    const int r0 = wave * 16 + (lane >> 2);
    const int r1 = 64 + r0;
    const int c  = lane & 3;
    const int kg0 = c ^ ((r0 >> 1) & 3);
    const int kg1 = c ^ ((r1 >> 1) & 3);

    const u16* pA0h = Ah + (size_t)(bm + r0) * K + 8 * kg0;
    const u16* pA1h = Ah + (size_t)(bm + r1) * K + 8 * kg1;
    const u16* pA0l = Al + (size_t)(bm + r0) * K + 8 * kg0;
    const u16* pA1l = Al + (size_t)(bm + r1) * K + 8 * kg1;
    const u16* pB0h = Bh + (size_t)(bn + r0) * K + 8 * kg0;
    const u16* pB1h = Bh + (size_t)(bn + r1) * K + 8 * kg1;
    const u16* pB0l = Bl + (size_t)(bn + r0) * K + 8 * kg0;
    const u16* pB1l = Bl + (size_t)(bn + r1) * K + 8 * kg1;

    char* ldsb = (char*)lds;
    char* dA0h = ldsb +     0 + wave * 1024;
    char* dA1h = ldsb +  4096 + wave * 1024;
    char* dA0l = ldsb +  8192 + wave * 1024;
    char* dA1l = ldsb + 12288 + wave * 1024;
    char* dB0h = ldsb + 16384 + wave * 1024;
    char* dB1h = ldsb + 20480 + wave * 1024;
    char* dB0l = ldsb + 24576 + wave * 1024;
    char* dB1l = ldsb + 28672 + wave * 1024;

    const int am0 = (wave >> 1) * 64;
    const int bn0 = (wave & 1) * 64;
    const int l15 = lane & 15;
    const int lg  = lane >> 4;

    f32x4 acc[4][4] = {};

    const int nk = K >> 5;
    for (int ks = 0; ks < nk; ++ks) {
        __syncthreads();
        load_lds16(pA0h, dA0h); load_lds16(pA1h, dA1h);
        load_lds16(pA0l, dA0l); load_lds16(pA1l, dA1l);
        load_lds16(pB0h, dB0h); load_lds16(pB1h, dB1h);
        load_lds16(pB0l, dB0l); load_lds16(pB1l, dB1l);
        pA0h += 32; pA1h += 32; pA0l += 32; pA1l += 32;
        pB0h += 32; pB1h += 32; pB0l += 32; pB1l += 32;
        __syncthreads();

        bf16x8 ah[4], al[4];
        #pragma unroll
        for (int fm = 0; fm < 4; ++fm) {
            const int ar = am0 + fm * 16 + l15;
            const int ph = (lg ^ ((ar >> 1) & 3)) * 8;
            ah[fm] = *(const bf16x8*)&sAh[ar * 32 + ph];
            al[fm] = *(const bf16x8*)&sAl[ar * 32 + ph];
        }
        #pragma unroll
        for (int fn = 0; fn < 4; ++fn) {
            const int br = bn0 + fn * 16 + l15;
            const int ph = (lg ^ ((br >> 1) & 3)) * 8;
            const bf16x8 bh = *(const bf16x8*)&sBh[br * 32 + ph];
            const bf16x8 bl = *(const bf16x8*)&sBl[br * 32 + ph];
            #pragma unroll
            for (int fm = 0; fm < 4; ++fm) {
                acc[fm][fn] = __builtin_amdgcn_mfma_f32_16x16x32_bf16(
                    ah[fm], bh, acc[fm][fn], 0, 0, 0);
                acc[fm][fn] = __builtin_amdgcn_mfma_f32_16x16x32_bf16(
                    ah[fm], bl, acc[fm][fn], 0, 0, 0);
                acc[fm][fn] = __builtin_amdgcn_mfma_f32_16x16x32_bf16(
                    al[fm], bh, acc[fm][fn], 0, 0, 0);
            }
        }
    }

    // ---- epilogue: D col = lane&15, row = (lane>>4)*4 + j ----
    #pragma unroll
    for (int fn = 0; fn < 4; ++fn) {
        const int cc = bn + bn0 + fn * 16 + l15;
        const float bv = bias[cc];
        #pragma unroll
        for (int fm = 0; fm < 4; ++fm) {
            const int rbase = bm + am0 + fm * 16 + lg * 4;
            const f32x4 v = acc[fm][fn];
            #pragma unroll
            for (int j = 0; j < 4; ++j) {
                const int r = rbase + j;
                if (r < M) {
                    float o = v[j] + bv;
                    if (RELU6) o = fminf(fmaxf(o, 0.0f), 6.0f);
                    if (RES)   o += res[(size_t)r * N + cc];
                    if (OMODE == 0) {
                        Cf[(size_t)r * N + cc] = o;
                    } else if (OMODE == 1) {
                        const u16 h = f2bf(o);
                        Ch[(size_t)r * N + cc] = h;
                        Cl[(size_t)r * N + cc] = f2bf(o - bf2f(h));
                    } else {
                        // QKV scatter: cc -> (s, hh, d); r -> (b, n)
                        const int s   = bn / 768;          // uniform per block
                        const int rem = cc - s * 768;
                        const int hh  = rem >> 6, d = rem & 63;
                        const int b   = r / 577, n = r - b * 577;
                        const u16 hb = f2bf(o);
                        const u16 lb = f2bf(o - bf2f(hb));
                        if (s == 0) {
                            const size_t dst = (size_t)((b * 12 + hh) * 577 + n) * 64 + d;
                            Qh_[dst] = hb; Ql_[dst] = lb;
                        } else if (s == 1) {
                            const size_t dst = (size_t)((b * 12 + hh) * 577 + n) * 64 + d;
                            Kh_[dst] = hb; Kl_[dst] = lb;
                        } else {
                            const size_t dst = ((size_t)(b * 12 + hh) * 64 + d) * 640 + n;
                            Vth_[dst] = hb; Vtl_[dst] = lb;
                        }
                    }
                }
            }
        }
    }
}

// --------------------------- MFMA flash attention ---------------------------
// Block: one (b,h), 64 q rows. 4 waves x 16 q rows.
// S^T = mfma(K, Q): col=l15=q, row=kv. Softmax per lane + shfl_xor(16,32).
// P round-trips LDS (per-wave region) to re-fragment; O^T = mfma(Vt, P).
__global__ __launch_bounds__(256)
void attn_mfma(const u16* __restrict__ Qh, const u16* __restrict__ Ql,
               const u16* __restrict__ Kh, const u16* __restrict__ Kl,
               const u16* __restrict__ Vth, const u16* __restrict__ Vtl,
               u16* __restrict__ Oh, u16* __restrict__ Ol)
{
    constexpr int SEQ = 577, NP = 640;
    __shared__ u16 sKh[4096], sKl[4096], sVh[4096], sVl[4096];  // [row][64]
    __shared__ u16 sPh[4][16 * 72], sPl[4][16 * 72];            // per-wave P

    const int tid  = threadIdx.x;
    const int wave = tid >> 6;
    const int lane = tid & 63;
    const int l15 = lane & 15, lg = lane >> 4;
    const int q0 = blockIdx.x * 64;
    const int bh = blockIdx.y;

    const size_t qkBase = (size_t)bh * SEQ * 64;
    const size_t vBase  = (size_t)bh * 64 * NP;

    // Q fragments (2 k-steps x hi/lo), loaded once
    bf16x8 qfh[2], qfl[2];
    {
        const size_t ro = qkBase + (size_t)(q0 + wave * 16 + l15) * 64;
        #pragma unroll
        for (int ks = 0; ks < 2; ++ks) {
            qfh[ks] = *(const bf16x8*)&Qh[ro + (ks * 4 + lg) * 8];
            qfl[ks] = *(const bf16x8*)&Ql[ro + (ks * 4 + lg) * 8];
        }
    }

    const int srow = lane >> 3;   // staging: row within 8-row slice
    const int sc   = lane & 7;    // staging: phys 16B chunk

    f32x4 oacc[4] = {};
    float mrun = -1e30f, lrun = 0.0f;

    for (int kv0 = 0; kv0 < SEQ; kv0 += 64) {
        __syncthreads();
        // ---- stage K[kv][64] and Vt[d][64kv] tiles (XOR-swizzled source) ----
        #pragma unroll
        for (int t = 0; t < 2; ++t) {
            const int row = wave * 16 + t * 8 + srow;
            const int lc  = sc ^ (row & 7);
            const size_t ko = qkBase + (size_t)(kv0 + row) * 64 + lc * 8;
            const size_t vo = vBase + (size_t)row * NP + kv0 + lc * 8;
            char* const dst = (char*)nullptr;
            (void)dst;
            load_lds16(Kh + ko, (char*)sKh + wave * 2048 + t * 1024);
            load_lds16(Kl + ko, (char*)sKl + wave * 2048 + t * 1024);
            load_lds16(Vth + vo, (char*)sVh + wave * 2048 + t * 1024);
            load_lds16(Vtl + vo, (char*)sVl + wave * 2048 + t * 1024);
        }
        __syncthreads();

        // ---- S^T fragments: mfma(K, Q) ----
        f32x4 sacc[4] = {};
        #pragma unroll
        for (int fkv = 0; fkv < 4; ++fkv) {
            const int row = fkv * 16 + l15;
            #pragma unroll
            for (int ks = 0; ks < 2; ++ks) {
                const int ph = ((ks * 4 + lg) ^ (row & 7)) * 8;
                const bf16x8 kh = *(const bf16x8*)&sKh[row * 64 + ph];
                const bf16x8 kl = *(const bf16x8*)&sKl[row * 64 + ph];
                sacc[fkv] = __builtin_amdgcn_mfma_f32_16x16x32_bf16(
                    kh, qfh[ks], sacc[fkv], 0, 0, 0);
                sacc[fkv] = __builtin_amdgcn_mfma_f32_16x16x32_bf16(
                    kh, qfl[ks], sacc[fkv], 0, 0, 0);
                sacc[fkv] = __builtin_amdgcn_mfma_f32_16x16x32_bf16(
                    kl, qfh[ks], sacc[fkv], 0, 0, 0);
            }
        }

        // ---- online softmax (lane holds 16 kv values of q=l15) ----
        float p[4][4];
        float mt = -1e30f;
        const bool tail = (kv0 + 64 > SEQ);
        #pragma unroll
        for (int fkv = 0; fkv < 4; ++fkv)
            #pragma unroll
            for (int j = 0; j < 4; ++j) {
                float sv = sacc[fkv][j] * 0.125f;
                if (tail && (kv0 + fkv * 16 + lg * 4 + j >= SEQ)) sv = -1e30f;
                p[fkv][j] = sv;
                mt = fmaxf(mt, sv);
            }
        mt = fmaxf(mt, __shfl_xor(mt, 16));
        mt = fmaxf(mt, __shfl_xor(mt, 32));
        const float mnew = fmaxf(mrun, mt);
        const float corr = __expf(mrun - mnew);
        float rs = 0.0f;
        #pragma unroll
        for (int fkv = 0; fkv < 4; ++fkv)
            #pragma unroll
            for (int j = 0; j < 4; ++j) {
                p[fkv][j] = __expf(p[fkv][j] - mnew);
                rs += p[fkv][j];
            }
        rs += __shfl_xor(rs, 16);
        rs += __shfl_xor(rs, 32);
        lrun = lrun * corr + rs;
        mrun = mnew;
        #pragma unroll
        for (int fd = 0; fd < 4; ++fd)
            #pragma unroll
            for (int j = 0; j < 4; ++j) oacc[fd][j] *= corr;

        // ---- P -> per-wave LDS (hi/lo), then re-fragment ----
        u16* phr = &sPh[wave][l15 * 72];
        u16* plr = &sPl[wave][l15 * 72];
        #pragma unroll
        for (int fkv = 0; fkv < 4; ++fkv) {
            ushort4 hv, lv;
            hv.x = f2bf(p[fkv][0]); lv.x = f2bf(p[fkv][0] - bf2f(hv.x));
            hv.y = f2bf(p[fkv][1]); lv.y = f2bf(p[fkv][1] - bf2f(hv.y));
            hv.z = f2bf(p[fkv][2]); lv.z = f2bf(p[fkv][2] - bf2f(hv.z));
            hv.w = f2bf(p[fkv][3]); lv.w = f2bf(p[fkv][3] - bf2f(hv.w));
            *(ushort4*)&phr[fkv * 16 + lg * 4] = hv;
            *(ushort4*)&plr[fkv * 16 + lg * 4] = lv;
        }

        // ---- O^T += mfma(Vt, P) ----
        #pragma unroll
        for (int ks = 0; ks < 2; ++ks) {
            const bf16x8 pbh = *(const bf16x8*)&sPh[wave][l15 * 72 + (ks * 4 + lg) * 8];
            const bf16x8 pbl = *(const bf16x8*)&sPl[wave][l15 * 72 + (ks * 4 + lg) * 8];
            #pragma unroll
            for (int fd = 0; fd < 4; ++fd) {
                const int row = fd * 16 + l15;
                const int ph = ((ks * 4 + lg) ^ (row & 7)) * 8;
                const bf16x8 vh = *(const bf16x8*)&sVh[row * 64 + ph];
                const bf16x8 vl = *(const bf16x8*)&sVl[row * 64 + ph];
                oacc[fd] = __builtin_amdgcn_mfma_f32_16x16x32_bf16(
                    vh, pbh, oacc[fd], 0, 0, 0);
                oacc[fd] = __builtin_amdgcn_mfma_f32_16x16x32_bf16(
                    vh, pbl, oacc[fd], 0, 0, 0);
                oacc[fd] = __builtin_amdgcn_mfma_f32_16x16x32_bf16(
                    vl, pbh, oacc[fd], 0, 0, 0);
            }
        }
    }

    // ---- store O (lane owns q=l15, d = fd*16 + lg*4 + j) ----
    const int q = q0 + wave * 16 + l15;
    if (q < SEQ) {
        const float inv = 1.0f / lrun;
        const int b = bh / 12, h = bh % 12;
        const size_t rowo = ((size_t)b * SEQ + q) * 768 + h * 64;
        #pragma unroll
        for (int fd = 0; fd < 4; ++fd) {
            const float o0 = oacc[fd][0] * inv, o1 = oacc[fd][1] * inv;
            const float o2 = oacc[fd][2] * inv, o3 = oacc[fd][3] * inv;
            ushort4 hv, lv;
            hv.x = f2bf(o0); lv.x = f2bf(o0 - bf2f(hv.x));
            hv.y = f2bf(o1); lv.y = f2bf(o1 - bf2f(hv.y));
            hv.z = f2bf(o2); lv.z = f2bf(o2 - bf2f(hv.z));
            hv.w = f2bf(o3); lv.w = f2bf(o3 - bf2f(hv.w));
            *(ushort4*)&Oh[rowo + fd * 16 + lg * 4] = hv;
            *(ushort4*)&Ol[rowo + fd * 16 + lg * 4] = lv;
        }
    }
}

// ------------------------------- launch ------------------------------------
extern "C" void kernel_launch(void* const* d_in, const int* in_sizes, int n_in,
                              void* d_out, int out_size, void* d_ws, size_t ws_size,
                              hipStream_t stream)
{
    const float* x      = (const float*)d_in[0];
    const float* ln1_g  = (const float*)d_in[1];
    const float* ln1_b  = (const float*)d_in[2];
    const float* ln2_g  = (const float*)d_in[3];
    const float* ln2_b  = (const float*)d_in[4];
    const float* w_qkv  = (const float*)d_in[5];
    const float* b_qkv  = (const float*)d_in[6];
    const float* w_proj = (const float*)d_in[7];
    const float* b_proj = (const float*)d_in[8];
    const float* w_fc1  = (const float*)d_in[9];
    const float* b_fc1  = (const float*)d_in[10];
    const float* w_fc2  = (const float*)d_in[11];
    const float* b_fc2  = (const float*)d_in[12];
    float* out = (float*)d_out;

    const int M  = 18464;
    const int Mp = 18560;

    // ---- workspace carve-up (sizes are multiples of 256B) ----
    char* p = (char*)d_ws;
    u16* Wqkv_h = (u16*)p;   p += (size_t)2304 * 768 * 2;
    u16* Wqkv_l = (u16*)p;   p += (size_t)2304 * 768 * 2;
    u16* Wproj_h = (u16*)p;  p += (size_t)768 * 768 * 2;
    u16* Wproj_l = (u16*)p;  p += (size_t)768 * 768 * 2;
    u16* Wfc1_h = (u16*)p;   p += (size_t)3072 * 768 * 2;
    u16* Wfc1_l = (u16*)p;   p += (size_t)3072 * 768 * 2;
    u16* Wfc2_h = (u16*)p;   p += (size_t)768 * 3072 * 2;
    u16* Wfc2_l = (u16*)p;   p += (size_t)768 * 3072 * 2;
    u16* A_h = (u16*)p;      p += (size_t)Mp * 768 * 2;
    u16* A_l = (u16*)p;      p += (size_t)Mp * 768 * 2;
    const size_t QKB = ((size_t)384 * 577 * 64 + 8192) * 2;   // + OOB pad
    u16* Qh = (u16*)p;       p += QKB;
    u16* Ql = (u16*)p;       p += QKB;
    u16* Kh = (u16*)p;       p += QKB;
    u16* Kl = (u16*)p;       p += QKB;
    u16* Vth = (u16*)p;      p += (size_t)384 * 64 * 640 * 2;
    u16* Vtl = (u16*)p;      p += (size_t)384 * 64 * 640 * 2;
    // fc1 output (bf16 hi/lo) reuses the dead Q/K/Vt region after attention
    u16* fc1h = Qh;
    u16* fc1l = Qh + (size_t)9344 * 3072;

    // ---- weight prep ----
    wprep_kernel<<<dim3(72, 24),  256, 0, stream>>>(w_qkv,  Wqkv_h,  Wqkv_l,  768, 2304);
    wprep_kernel<<<dim3(24, 24),  256, 0, stream>>>(w_proj, Wproj_h, Wproj_l, 768, 768);
    wprep_kernel<<<dim3(96, 24),  256, 0, stream>>>(w_fc1,  Wfc1_h,  Wfc1_l,  768, 3072);
    wprep_kernel<<<dim3(24, 96),  256, 0, stream>>>(w_fc2,  Wfc2_h,  Wfc2_l,  3072, 768);

    // ---- ln1 ----
    ln_kernel<<<M, 256, 0, stream>>>(x, ln1_g, ln1_b, A_h, A_l);
    // ---- qkv projection, scattered into Q/K/Vt hi/lo ----
    mfma_gemm<0, 0, 2><<<dim3(18, 145), 256, 0, stream>>>(
        A_h, A_l, Wqkv_h, Wqkv_l, b_qkv, nullptr, nullptr, nullptr, nullptr,
        Qh, Ql, Kh, Kl, Vth, Vtl, M, 2304, 768);
    // ---- attention -> A (hi/lo) ----
    attn_mfma<<<dim3(10, 384), 256, 0, stream>>>(Qh, Ql, Kh, Kl, Vth, Vtl, A_h, A_l);
    // ---- x1 = attnO @ w_proj + b + x -> out ----
    mfma_gemm<0, 1, 0><<<dim3(6, 145), 256, 0, stream>>>(
        A_h, A_l, Wproj_h, Wproj_l, b_proj, x, out, nullptr, nullptr,
        nullptr, nullptr, nullptr, nullptr, nullptr, nullptr, M, 768, 768);
    // ---- ln2 ----
    ln_kernel<<<M, 256, 0, stream>>>(out, ln2_g, ln2_b, A_h, A_l);
    // ---- MLP in 2 row chunks ----
    const int CH = 9344;
    for (int r0 = 0; r0 < M; r0 += CH) {
        const int mc = (M - r0 < CH) ? (M - r0) : CH;
        const int mtiles = (mc + 127) / 128;
        mfma_gemm<1, 0, 1><<<dim3(24, mtiles), 256, 0, stream>>>(
            A_h + (size_t)r0 * 768, A_l + (size_t)r0 * 768,
            Wfc1_h, Wfc1_l, b_fc1, nullptr, nullptr, fc1h, fc1l,
            nullptr, nullptr, nullptr, nullptr, nullptr, nullptr,
            mc, 3072, 768);
        mfma_gemm<0, 1, 0><<<dim3(6, mtiles), 256, 0, stream>>>(
            fc1h, fc1l, Wfc2_h, Wfc2_l, b_fc2,
            out + (size_t)r0 * 768, out + (size_t)r0 * 768, nullptr, nullptr,
            nullptr, nullptr, nullptr, nullptr, nullptr, nullptr,
            mc, 768, 3072);
    }
}